// Round 2
// baseline (135.757 us; speedup 1.0000x reference)
//
#include <hip/hip_runtime.h>
#include <float.h>

#define BB 16
#define MM 32
#define KK 20
#define AA 8
#define TT 30
#define TD 60          // T*D floats per trajectory
#define NS 15          // float4 steps per trajectory (2 t-steps each)
#define KT 22          // target rows: 20 real + gt (row 20) + dummy (row 21)
#define PDS 21         // pd row stride in floats
#define GRID (BB * AA * (MM / 2))   // 2048 blocks

typedef float v2f __attribute__((ext_vector_type(2)));

// Module-global election counter. NEVER reset: election is on
// (t+1) % GRID == 0, so it is robust to graph replays, rocprof
// counter-group re-runs, and any stale value being a multiple of GRID.
// Lives in module .data -> immune to the harness's ws poison-fill.
__device__ unsigned int g_epoch = 0;

__device__ __forceinline__ float ld_agent(const float* p) {
    return __hip_atomic_load(p, __ATOMIC_RELAXED, __HIP_MEMORY_SCOPE_AGENT);
}
__device__ __forceinline__ void st_agent(float* p, float v) {
    __hip_atomic_store(p, v, __ATOMIC_RELAXED, __HIP_MEMORY_SCOPE_AGENT);
}

// One block = 2 waves = 2 m's sharing the target tile, for a fixed (b, a).
// grid = 2048 -> 8 blocks/CU (LDS 18.25 KB) -> 16 waves/CU.
// Staged float4 is component-swizzled to (x_t, x_{t+1}, y_t, y_{t+1}) so the
// inner loop is pure <2 x float> arithmetic -> v_pk_{sub,mul,fma,add}_f32:
// 7 instr per distance-pair (2 pk_sub, pk_mul+pk_fma, 2 sqrt, pk_add) vs 12.
// Last block (agent-scope monotonic-epoch election) performs the final
// reduction, eliminating the second dispatch and its launch gap.
__global__ __launch_bounds__(128, 4) void imle_fused_kernel(
    const float* __restrict__ gen,   // B M K A T D
    const float* __restrict__ tgt,   // B K A T D
    const float* __restrict__ gt,    // B A T D
    float* __restrict__ ws_cham,     // [B][M][A]
    float* __restrict__ ws_gt,       // [B][M][A]
    float* __restrict__ out)         // [3]
{
    __shared__ float4 sg[2][KK][NS];   // 2 m-slices of gen, x50, swizzled
    __shared__ float4 st[KT][NS];      // target rows (x50) + gt row + dummy
    __shared__ float  pd[2][KK][PDS];  // per-m pairwise mean distances
    __shared__ unsigned int is_last;

    const int blk = blockIdx.x;        // grid = 2048
    const int mg = blk & 15;           // m-group (M/2 = 16)
    const int a  = (blk >> 4) & 7;
    const int b  = blk >> 7;
    const int m0 = mg * 2;
    const int tid = threadIdx.x;

    // ---- stage gen: 2m x 20k rows of 15 float4, swizzle (x1,y1,x2,y2)->(x1,x2,y1,y2) ----
    for (int idx = tid; idx < 40 * NS; idx += 128) {
        int row = idx / NS, q = idx - row * NS;
        int mi = row / KK, k = row - mi * KK;
        float4 v = ((const float4*)(gen +
            (size_t)(((b * MM + m0 + mi) * KK + k) * AA + a) * TD))[q];
        sg[mi][k][q] = make_float4(v.x * 50.f, v.z * 50.f, v.y * 50.f, v.w * 50.f);
    }
    // ---- stage target rows 0..19 (x50), row 20 = gt (metric), row 21 = zeros ----
    for (int idx = tid; idx < KT * NS; idx += 128) {
        int row = idx / NS, q = idx - row * NS;
        float4 v;
        if (row < KK) {
            v = ((const float4*)(tgt + (size_t)((b * KK + row) * AA + a) * TD))[q];
            v = make_float4(v.x * 50.f, v.z * 50.f, v.y * 50.f, v.w * 50.f);
        } else if (row == KK) {
            v = ((const float4*)(gt + (size_t)(b * AA + a) * TD))[q];
            v = make_float4(v.x, v.z, v.y, v.w);
        } else {
            v = make_float4(0.f, 0.f, 0.f, 0.f);
        }
        st[row][q] = v;
    }
    __syncthreads();

    const int w = tid >> 6;        // wave id -> m offset (0 or 1)
    const int lane = tid & 63;

    // ---- pairwise distances: 4x2 register tile, software-pipelined s-loop ----
    if (lane < 55) {
        const int tk  = lane / 11;       // k  = tk + 5i
        const int tkp = lane - tk * 11;  // kp = tkp + 11j
        v2f acc[4][2] = {{{0.f,0.f},{0.f,0.f}},{{0.f,0.f},{0.f,0.f}},
                         {{0.f,0.f},{0.f,0.f}},{{0.f,0.f},{0.f,0.f}}};

        float4 gv[4], tv[2];
#pragma unroll
        for (int i = 0; i < 4; ++i) gv[i] = sg[w][tk + 5 * i][0];
        tv[0] = st[tkp][0];
        tv[1] = st[tkp + 11][0];

#pragma unroll 2
        for (int s = 0; s < NS - 1; ++s) {
            // prefetch s+1 (independent of current compute)
            float4 ngv[4], ntv[2];
#pragma unroll
            for (int i = 0; i < 4; ++i) ngv[i] = sg[w][tk + 5 * i][s + 1];
            ntv[0] = st[tkp][s + 1];
            ntv[1] = st[tkp + 11][s + 1];
            // compute on current: packed over the 2 t-steps in each float4
#pragma unroll
            for (int i = 0; i < 4; ++i) {
                v2f gx = {gv[i].x, gv[i].y};   // (x_t, x_{t+1})
                v2f gy = {gv[i].z, gv[i].w};   // (y_t, y_{t+1})
#pragma unroll
                for (int j = 0; j < 2; ++j) {
                    v2f dx = gx - (v2f){tv[j].x, tv[j].y};
                    v2f dy = gy - (v2f){tv[j].z, tv[j].w};
                    v2f sq = dy * dy + dx * dx;   // contracts to pk_fma(dy,dy, dx*dx)
                    acc[i][j] += (v2f){__builtin_amdgcn_sqrtf(sq.x),
                                       __builtin_amdgcn_sqrtf(sq.y)};
                }
            }
#pragma unroll
            for (int i = 0; i < 4; ++i) gv[i] = ngv[i];
            tv[0] = ntv[0];
            tv[1] = ntv[1];
        }
        // epilogue: s = NS-1
#pragma unroll
        for (int i = 0; i < 4; ++i) {
            v2f gx = {gv[i].x, gv[i].y};
            v2f gy = {gv[i].z, gv[i].w};
#pragma unroll
            for (int j = 0; j < 2; ++j) {
                v2f dx = gx - (v2f){tv[j].x, tv[j].y};
                v2f dy = gy - (v2f){tv[j].z, tv[j].w};
                v2f sq = dy * dy + dx * dx;
                acc[i][j] += (v2f){__builtin_amdgcn_sqrtf(sq.x),
                                   __builtin_amdgcn_sqrtf(sq.y)};
            }
        }

        const float inv_t = 1.0f / TT;
#pragma unroll
        for (int i = 0; i < 4; ++i) {
            pd[w][tk + 5 * i][tkp] = (acc[i][0].x + acc[i][0].y) * inv_t;
            if (tkp + 11 <= KK)                           // col 21 is dummy
                pd[w][tk + 5 * i][tkp + 11] = (acc[i][1].x + acc[i][1].y) * inv_t;
        }
    }
    __syncthreads();

    // ---- row/col mins over 20x20 + gt col, per wave / per m ----
    float v = 0.f;
    float dg = FLT_MAX;
    if (lane < KK) {
        float rm = pd[w][lane][0];
#pragma unroll
        for (int j = 1; j < KK; ++j) rm = fminf(rm, pd[w][lane][j]);
        float cm = pd[w][0][lane];
#pragma unroll
        for (int j = 1; j < KK; ++j) cm = fminf(cm, pd[w][j][lane]);
        v = rm + cm;
        dg = pd[w][lane][KK];   // gt column
    }
#pragma unroll
    for (int off = 16; off > 0; off >>= 1) {
        v += __shfl_xor(v, off, 32);
        dg = fminf(dg, __shfl_xor(dg, off, 32));
    }

    if (lane == 0) {
        const size_t o = ((size_t)b * MM + (m0 + w)) * AA + a;
        st_agent(&ws_cham[o], v * (1.0f / KK));   // agent-scope: visible cross-XCD
        st_agent(&ws_gt[o], dg);
    }
    __syncthreads();   // both waves' ws stores done before election

    // ---- last-block election (monotonic epoch, never reset) ----
    if (tid == 0) {
        __threadfence();
        unsigned t = __hip_atomic_fetch_add(&g_epoch, 1u, __ATOMIC_ACQ_REL,
                                            __HIP_MEMORY_SCOPE_AGENT);
        is_last = ((t + 1u) % (unsigned)GRID == 0u) ? 1u : 0u;
    }
    __syncthreads();
    if (!is_last) return;

    // ---- final reduction (one block; reuse sg as scratch) ----
    __threadfence();
    float* ch = (float*)sg;        // 512 floats
    float* gm = ch + 512;          // 512 floats
    float* mc = ch + 1024;         // 16 floats
    float* mgt = ch + 1040;        // 16 floats

    for (int p = tid; p < BB * MM; p += 128) {
        const float* pc = ws_cham + (size_t)p * AA;
        const float* pg = ws_gt   + (size_t)p * AA;
        float sc = 0.f, sgg = 0.f;
#pragma unroll
        for (int a2 = 0; a2 < AA; ++a2) {
            sc  += ld_agent(pc + a2);
            sgg += ld_agent(pg + a2);
        }
        ch[p] = sc * (1.0f / AA);
        gm[p] = sgg * (1.0f / AA);
    }
    __syncthreads();

    if (tid < BB) {
        float c = ch[tid * MM], g = gm[tid * MM];
        for (int j = 1; j < MM; ++j) {
            c = fminf(c, ch[tid * MM + j]);
            g = fminf(g, gm[tid * MM + j]);
        }
        mc[tid] = c;
        mgt[tid] = g;
    }
    __syncthreads();

    if (tid == 0) {
        float lc = 0.f, lg = 0.f;
        for (int j = 0; j < BB; ++j) { lc += mc[j]; lg += mgt[j]; }
        lc *= (1.0f / BB);
        lg *= (1.0f / BB);
        out[0] = lc + lg;
        out[1] = lc;
        out[2] = lg;
    }
}

extern "C" void kernel_launch(void* const* d_in, const int* in_sizes, int n_in,
                              void* d_out, int out_size, void* d_ws, size_t ws_size,
                              hipStream_t stream) {
    const float* gen = (const float*)d_in[0];
    const float* tgt = (const float*)d_in[1];
    const float* gt  = (const float*)d_in[2];
    float* ws_cham = (float*)d_ws;                 // B*M*A floats
    float* ws_gt   = ws_cham + BB * MM * AA;       // B*M*A floats
    float* out     = (float*)d_out;

    imle_fused_kernel<<<GRID, 128, 0, stream>>>(gen, tgt, gt, ws_cham, ws_gt, out);
}

// Round 3
// 101.076 us; speedup vs baseline: 1.3431x; 1.3431x over previous
//
#include <hip/hip_runtime.h>
#include <float.h>

#define BB 16
#define MM 32
#define KK 20
#define AA 8
#define TT 30
#define TD 60          // T*D floats per trajectory
#define NS 15          // float4 steps per trajectory (2 t-steps each)
#define KT 22          // target rows: 20 real + gt (row 20) + dummy (row 21)
#define PDS 21         // pd row stride in floats
#define GRID (BB * AA * (MM / 2))   // 2048 blocks

typedef float v2f __attribute__((ext_vector_type(2)));

// Module-global election counter. NEVER reset: election is on
// (t+1) % GRID == 0, robust to graph replays / rocprof re-runs.
__device__ unsigned int g_epoch = 0;

// Agent-scope (sc1) accesses: performed at the MALL (coherence point),
// bypassing the non-coherent per-XCD L2s. No fences / cache maintenance
// needed anywhere -- that was the Round-2 regression (+45us of
// buffer_wbl2/buffer_inv from __threadfence + ACQ_REL, once per block).
__device__ __forceinline__ float ld_agent(const float* p) {
    return __hip_atomic_load(p, __ATOMIC_RELAXED, __HIP_MEMORY_SCOPE_AGENT);
}
__device__ __forceinline__ void st_agent(float* p, float v) {
    __hip_atomic_store(p, v, __ATOMIC_RELAXED, __HIP_MEMORY_SCOPE_AGENT);
}

// One block = 2 waves = 2 m's sharing the target tile, for a fixed (b, a).
// grid = 2048 -> 8 blocks/CU (LDS 18.25 KB) -> 16 waves/CU.
// Staged float4 is component-swizzled to (x_t, x_{t+1}, y_t, y_{t+1}) so the
// inner loop is pure <2 x float> arithmetic -> v_pk_{mul,fma,add}_f32.
// Last block (relaxed agent-scope epoch election) does the final reduction.
__global__ __launch_bounds__(128, 4) void imle_fused_kernel(
    const float* __restrict__ gen,   // B M K A T D
    const float* __restrict__ tgt,   // B K A T D
    const float* __restrict__ gt,    // B A T D
    float* __restrict__ ws_cham,     // [B][M][A]
    float* __restrict__ ws_gt,       // [B][M][A]
    float* __restrict__ out)         // [3]
{
    __shared__ float4 sg[2][KK][NS];   // 2 m-slices of gen, x50, swizzled
    __shared__ float4 st[KT][NS];      // target rows (x50) + gt row + dummy
    __shared__ float  pd[2][KK][PDS];  // per-m pairwise mean distances
    __shared__ unsigned int is_last;

    const int blk = blockIdx.x;        // grid = 2048
    const int mg = blk & 15;           // m-group (M/2 = 16)
    const int a  = (blk >> 4) & 7;
    const int b  = blk >> 7;
    const int m0 = mg * 2;
    const int tid = threadIdx.x;

    // ---- stage gen: 2m x 20k rows of 15 float4, swizzle (x1,y1,x2,y2)->(x1,x2,y1,y2) ----
    for (int idx = tid; idx < 40 * NS; idx += 128) {
        int row = idx / NS, q = idx - row * NS;
        int mi = row / KK, k = row - mi * KK;
        float4 v = ((const float4*)(gen +
            (size_t)(((b * MM + m0 + mi) * KK + k) * AA + a) * TD))[q];
        sg[mi][k][q] = make_float4(v.x * 50.f, v.z * 50.f, v.y * 50.f, v.w * 50.f);
    }
    // ---- stage target rows 0..19 (x50), row 20 = gt (metric), row 21 = zeros ----
    for (int idx = tid; idx < KT * NS; idx += 128) {
        int row = idx / NS, q = idx - row * NS;
        float4 v;
        if (row < KK) {
            v = ((const float4*)(tgt + (size_t)((b * KK + row) * AA + a) * TD))[q];
            v = make_float4(v.x * 50.f, v.z * 50.f, v.y * 50.f, v.w * 50.f);
        } else if (row == KK) {
            v = ((const float4*)(gt + (size_t)(b * AA + a) * TD))[q];
            v = make_float4(v.x, v.z, v.y, v.w);
        } else {
            v = make_float4(0.f, 0.f, 0.f, 0.f);
        }
        st[row][q] = v;
    }
    __syncthreads();

    const int w = tid >> 6;        // wave id -> m offset (0 or 1)
    const int lane = tid & 63;

    // ---- pairwise distances: 4x2 register tile, software-pipelined s-loop ----
    if (lane < 55) {
        const int tk  = lane / 11;       // k  = tk + 5i
        const int tkp = lane - tk * 11;  // kp = tkp + 11j
        v2f acc[4][2] = {{{0.f,0.f},{0.f,0.f}},{{0.f,0.f},{0.f,0.f}},
                         {{0.f,0.f},{0.f,0.f}},{{0.f,0.f},{0.f,0.f}}};

        float4 gv[4], tv[2];
#pragma unroll
        for (int i = 0; i < 4; ++i) gv[i] = sg[w][tk + 5 * i][0];
        tv[0] = st[tkp][0];
        tv[1] = st[tkp + 11][0];

#pragma unroll 2
        for (int s = 0; s < NS - 1; ++s) {
            // prefetch s+1 (independent of current compute)
            float4 ngv[4], ntv[2];
#pragma unroll
            for (int i = 0; i < 4; ++i) ngv[i] = sg[w][tk + 5 * i][s + 1];
            ntv[0] = st[tkp][s + 1];
            ntv[1] = st[tkp + 11][s + 1];
            // compute on current: packed over the 2 t-steps in each float4
#pragma unroll
            for (int i = 0; i < 4; ++i) {
                v2f gx = {gv[i].x, gv[i].y};   // (x_t, x_{t+1})
                v2f gy = {gv[i].z, gv[i].w};   // (y_t, y_{t+1})
#pragma unroll
                for (int j = 0; j < 2; ++j) {
                    v2f dx = gx - (v2f){tv[j].x, tv[j].y};
                    v2f dy = gy - (v2f){tv[j].z, tv[j].w};
                    v2f sq = dy * dy + dx * dx;   // contracts to pk_fma(dy,dy, dx*dx)
                    acc[i][j] += (v2f){__builtin_amdgcn_sqrtf(sq.x),
                                       __builtin_amdgcn_sqrtf(sq.y)};
                }
            }
#pragma unroll
            for (int i = 0; i < 4; ++i) gv[i] = ngv[i];
            tv[0] = ntv[0];
            tv[1] = ntv[1];
        }
        // epilogue: s = NS-1
#pragma unroll
        for (int i = 0; i < 4; ++i) {
            v2f gx = {gv[i].x, gv[i].y};
            v2f gy = {gv[i].z, gv[i].w};
#pragma unroll
            for (int j = 0; j < 2; ++j) {
                v2f dx = gx - (v2f){tv[j].x, tv[j].y};
                v2f dy = gy - (v2f){tv[j].z, tv[j].w};
                v2f sq = dy * dy + dx * dx;
                acc[i][j] += (v2f){__builtin_amdgcn_sqrtf(sq.x),
                                   __builtin_amdgcn_sqrtf(sq.y)};
            }
        }

        const float inv_t = 1.0f / TT;
#pragma unroll
        for (int i = 0; i < 4; ++i) {
            pd[w][tk + 5 * i][tkp] = (acc[i][0].x + acc[i][0].y) * inv_t;
            if (tkp + 11 <= KK)                           // col 21 is dummy
                pd[w][tk + 5 * i][tkp + 11] = (acc[i][1].x + acc[i][1].y) * inv_t;
        }
    }
    __syncthreads();

    // ---- row/col mins over 20x20 + gt col, per wave / per m ----
    float v = 0.f;
    float dg = FLT_MAX;
    if (lane < KK) {
        float rm = pd[w][lane][0];
#pragma unroll
        for (int j = 1; j < KK; ++j) rm = fminf(rm, pd[w][lane][j]);
        float cm = pd[w][0][lane];
#pragma unroll
        for (int j = 1; j < KK; ++j) cm = fminf(cm, pd[w][j][lane]);
        v = rm + cm;
        dg = pd[w][lane][KK];   // gt column
    }
#pragma unroll
    for (int off = 16; off > 0; off >>= 1) {
        v += __shfl_xor(v, off, 32);
        dg = fminf(dg, __shfl_xor(dg, off, 32));
    }

    if (lane == 0) {
        const size_t o = ((size_t)b * MM + (m0 + w)) * AA + a;
        st_agent(&ws_cham[o], v * (1.0f / KK));   // sc1: lands at MALL
        st_agent(&ws_gt[o], dg);
    }
    __syncthreads();   // drains both waves' stores (vmcnt 0 before s_barrier)

    // ---- last-block election: RELAXED RMW, no fences, no L2 maintenance ----
    if (tid == 0) {
        asm volatile("s_waitcnt vmcnt(0)" ::: "memory");  // belt-and-braces drain
        unsigned t = __hip_atomic_fetch_add(&g_epoch, 1u, __ATOMIC_RELAXED,
                                            __HIP_MEMORY_SCOPE_AGENT);
        is_last = ((t + 1u) % (unsigned)GRID == 0u) ? 1u : 0u;
    }
    __syncthreads();
    if (!is_last) return;
    asm volatile("" ::: "memory");   // keep reads below the election

    // ---- final reduction (one block; reuse sg as scratch) ----
    float* ch = (float*)sg;        // 512 floats
    float* gm = ch + 512;          // 512 floats
    float* mc = ch + 1024;         // 16 floats
    float* mgt = ch + 1040;        // 16 floats

    for (int p = tid; p < BB * MM; p += 128) {
        const float* pc = ws_cham + (size_t)p * AA;
        const float* pg = ws_gt   + (size_t)p * AA;
        float sc = 0.f, sgg = 0.f;
#pragma unroll
        for (int a2 = 0; a2 < AA; ++a2) {
            sc  += ld_agent(pc + a2);
            sgg += ld_agent(pg + a2);
        }
        ch[p] = sc * (1.0f / AA);
        gm[p] = sgg * (1.0f / AA);
    }
    __syncthreads();

    if (tid < BB) {
        float c = ch[tid * MM], g = gm[tid * MM];
        for (int j = 1; j < MM; ++j) {
            c = fminf(c, ch[tid * MM + j]);
            g = fminf(g, gm[tid * MM + j]);
        }
        mc[tid] = c;
        mgt[tid] = g;
    }
    __syncthreads();

    if (tid == 0) {
        float lc = 0.f, lg = 0.f;
        for (int j = 0; j < BB; ++j) { lc += mc[j]; lg += mgt[j]; }
        lc *= (1.0f / BB);
        lg *= (1.0f / BB);
        out[0] = lc + lg;
        out[1] = lc;
        out[2] = lg;
    }
}

extern "C" void kernel_launch(void* const* d_in, const int* in_sizes, int n_in,
                              void* d_out, int out_size, void* d_ws, size_t ws_size,
                              hipStream_t stream) {
    const float* gen = (const float*)d_in[0];
    const float* tgt = (const float*)d_in[1];
    const float* gt  = (const float*)d_in[2];
    float* ws_cham = (float*)d_ws;                 // B*M*A floats
    float* ws_gt   = ws_cham + BB * MM * AA;       // B*M*A floats
    float* out     = (float*)d_out;

    imle_fused_kernel<<<GRID, 128, 0, stream>>>(gen, tgt, gt, ws_cham, ws_gt, out);
}

// Round 4
// 81.585 us; speedup vs baseline: 1.6640x; 1.2389x over previous
//
#include <hip/hip_runtime.h>
#include <float.h>

#define BB 16
#define MM 32
#define KK 20
#define AA 8
#define TT 30
#define TD 60          // T*D floats per trajectory
#define NS 15          // float4 steps per trajectory (2 t-steps each)
#define KT 22          // target rows: 20 real + gt (row 20) + dummy (row 21)
#define PDS 21         // pd row stride in floats

typedef float v2f __attribute__((ext_vector_type(2)));

// One block = 2 waves = 2 m's sharing the target tile, for a fixed (b, a).
// grid = B*A*(M/2) = 2048 -> 8 blocks/CU (LDS 18.25 KB) -> 16 waves/CU.
// Staged float4 is component-swizzled to (x_t, x_{t+1}, y_t, y_{t+1}) so the
// inner loop is <2 x float> arithmetic -> v_pk_{add,mul,fma}_f32:
// 7 instr per distance-pair (2 pk_sub, pk_mul+pk_fma, 2 sqrt, pk_add) vs 12.
// Two-dispatch structure: R2/R3 showed single-dispatch last-block election
// costs ~20us (2048 same-address MALL atomics serialize) vs ~2us gap saved.
__global__ __launch_bounds__(128, 4) void imle_part_kernel(
    const float* __restrict__ gen,   // B M K A T D
    const float* __restrict__ tgt,   // B K A T D
    const float* __restrict__ gt,    // B A T D
    float* __restrict__ ws_cham,     // [B][M][A]
    float* __restrict__ ws_gt)       // [B][M][A]
{
    __shared__ float4 sg[2][KK][NS];   // 2 m-slices of gen, x50, swizzled
    __shared__ float4 st[KT][NS];      // target rows (x50) + gt row + dummy
    __shared__ float  pd[2][KK][PDS];  // per-m pairwise mean distances

    const int blk = blockIdx.x;        // grid = 2048
    const int mg = blk & 15;           // m-group (M/2 = 16)
    const int a  = (blk >> 4) & 7;
    const int b  = blk >> 7;
    const int m0 = mg * 2;
    const int tid = threadIdx.x;

    // ---- single merged staging loop: 600 gen float4 + 330 target float4 ----
    for (int idx = tid; idx < (40 + KT) * NS; idx += 128) {
        int row = idx / NS, q = idx - row * NS;
        if (row < 40) {                       // gen rows
            int mi = row / KK, k = row - mi * KK;
            float4 v = ((const float4*)(gen +
                (size_t)(((b * MM + m0 + mi) * KK + k) * AA + a) * TD))[q];
            sg[mi][k][q] = make_float4(v.x * 50.f, v.z * 50.f, v.y * 50.f, v.w * 50.f);
        } else {
            int r = row - 40;                 // target rows
            float4 v;
            if (r < KK) {
                v = ((const float4*)(tgt + (size_t)((b * KK + r) * AA + a) * TD))[q];
                v = make_float4(v.x * 50.f, v.z * 50.f, v.y * 50.f, v.w * 50.f);
            } else if (r == KK) {
                v = ((const float4*)(gt + (size_t)(b * AA + a) * TD))[q];
                v = make_float4(v.x, v.z, v.y, v.w);
            } else {
                v = make_float4(0.f, 0.f, 0.f, 0.f);
            }
            st[r][q] = v;
        }
    }
    __syncthreads();

    const int w = tid >> 6;        // wave id -> m offset (0 or 1)
    const int lane = tid & 63;

    // ---- pairwise distances: 4x2 register tile, software-pipelined s-loop ----
    if (lane < 55) {
        const int tk  = lane / 11;       // k  = tk + 5i
        const int tkp = lane - tk * 11;  // kp = tkp + 11j
        v2f acc[4][2] = {{{0.f,0.f},{0.f,0.f}},{{0.f,0.f},{0.f,0.f}},
                         {{0.f,0.f},{0.f,0.f}},{{0.f,0.f},{0.f,0.f}}};

        float4 gv[4], tv[2];
#pragma unroll
        for (int i = 0; i < 4; ++i) gv[i] = sg[w][tk + 5 * i][0];
        tv[0] = st[tkp][0];
        tv[1] = st[tkp + 11][0];

#pragma unroll 2
        for (int s = 0; s < NS - 1; ++s) {
            // prefetch s+1 (independent of current compute)
            float4 ngv[4], ntv[2];
#pragma unroll
            for (int i = 0; i < 4; ++i) ngv[i] = sg[w][tk + 5 * i][s + 1];
            ntv[0] = st[tkp][s + 1];
            ntv[1] = st[tkp + 11][s + 1];
            // compute on current: packed over the 2 t-steps in each float4
#pragma unroll
            for (int i = 0; i < 4; ++i) {
                v2f gx = {gv[i].x, gv[i].y};   // (x_t, x_{t+1})
                v2f gy = {gv[i].z, gv[i].w};   // (y_t, y_{t+1})
#pragma unroll
                for (int j = 0; j < 2; ++j) {
                    v2f dx = gx - (v2f){tv[j].x, tv[j].y};
                    v2f dy = gy - (v2f){tv[j].z, tv[j].w};
                    v2f sq = dy * dy + dx * dx;   // pk_fma(dy,dy, dx*dx)
                    acc[i][j] += (v2f){__builtin_amdgcn_sqrtf(sq.x),
                                       __builtin_amdgcn_sqrtf(sq.y)};
                }
            }
#pragma unroll
            for (int i = 0; i < 4; ++i) gv[i] = ngv[i];
            tv[0] = ntv[0];
            tv[1] = ntv[1];
        }
        // epilogue: s = NS-1
#pragma unroll
        for (int i = 0; i < 4; ++i) {
            v2f gx = {gv[i].x, gv[i].y};
            v2f gy = {gv[i].z, gv[i].w};
#pragma unroll
            for (int j = 0; j < 2; ++j) {
                v2f dx = gx - (v2f){tv[j].x, tv[j].y};
                v2f dy = gy - (v2f){tv[j].z, tv[j].w};
                v2f sq = dy * dy + dx * dx;
                acc[i][j] += (v2f){__builtin_amdgcn_sqrtf(sq.x),
                                   __builtin_amdgcn_sqrtf(sq.y)};
            }
        }

        const float inv_t = 1.0f / TT;
#pragma unroll
        for (int i = 0; i < 4; ++i) {
            pd[w][tk + 5 * i][tkp] = (acc[i][0].x + acc[i][0].y) * inv_t;
            if (tkp + 11 <= KK)                           // col 21 is dummy
                pd[w][tk + 5 * i][tkp + 11] = (acc[i][1].x + acc[i][1].y) * inv_t;
        }
    }
    __syncthreads();

    // ---- row/col mins over 20x20 + gt col, per wave / per m ----
    float v = 0.f;
    float dg = FLT_MAX;
    if (lane < KK) {
        float rm = pd[w][lane][0];
#pragma unroll
        for (int j = 1; j < KK; ++j) rm = fminf(rm, pd[w][lane][j]);
        float cm = pd[w][0][lane];
#pragma unroll
        for (int j = 1; j < KK; ++j) cm = fminf(cm, pd[w][j][lane]);
        v = rm + cm;
        dg = pd[w][lane][KK];   // gt column
    }
#pragma unroll
    for (int off = 16; off > 0; off >>= 1) {
        v += __shfl_xor(v, off, 32);
        dg = fminf(dg, __shfl_xor(dg, off, 32));
    }

    if (lane == 0) {
        const size_t o = ((size_t)b * MM + (m0 + w)) * AA + a;
        ws_cham[o] = v * (1.0f / KK);
        ws_gt[o]   = dg;
    }
}

// Single block: mean over A, min over M, mean over B, write 3 outputs.
// Dispatch boundary provides cross-XCD visibility of ws (runtime release/
// acquire around kernels) -- plain loads are fine, as in the 82us baseline.
__global__ __launch_bounds__(512) void imle_final_kernel(
    const float* __restrict__ ws_cham,
    const float* __restrict__ ws_gt,
    float* __restrict__ out)
{
    __shared__ float ch[BB * MM], gv[BB * MM];
    __shared__ float mch[BB], mgt[BB];
    const int tid = threadIdx.x;  // 512 == B*M
    const int b = tid / MM, m = tid % MM;

    float sc = 0.f, sg = 0.f;
#pragma unroll
    for (int a = 0; a < AA; ++a) {
        sc += ws_cham[((size_t)b * MM + m) * AA + a];
        sg += ws_gt[((size_t)b * MM + m) * AA + a];
    }
    ch[tid] = sc * (1.0f / AA);
    gv[tid] = sg * (1.0f / AA);
    __syncthreads();

    if (tid < BB) {
        float c = ch[tid * MM], g = gv[tid * MM];
        for (int j = 1; j < MM; ++j) {
            c = fminf(c, ch[tid * MM + j]);
            g = fminf(g, gv[tid * MM + j]);
        }
        mch[tid] = c;
        mgt[tid] = g;
    }
    __syncthreads();

    if (tid == 0) {
        float lc = 0.f, lg = 0.f;
        for (int j = 0; j < BB; ++j) { lc += mch[j]; lg += mgt[j]; }
        lc *= (1.0f / BB);
        lg *= (1.0f / BB);
        out[0] = lc + lg;
        out[1] = lc;
        out[2] = lg;
    }
}

extern "C" void kernel_launch(void* const* d_in, const int* in_sizes, int n_in,
                              void* d_out, int out_size, void* d_ws, size_t ws_size,
                              hipStream_t stream) {
    const float* gen = (const float*)d_in[0];
    const float* tgt = (const float*)d_in[1];
    const float* gt  = (const float*)d_in[2];
    float* ws_cham = (float*)d_ws;                 // B*M*A floats
    float* ws_gt   = ws_cham + BB * MM * AA;       // B*M*A floats
    float* out     = (float*)d_out;

    imle_part_kernel<<<BB * AA * (MM / 2), 128, 0, stream>>>(gen, tgt, gt, ws_cham, ws_gt);
    imle_final_kernel<<<1, 512, 0, stream>>>(ws_cham, ws_gt, out);
}